// Round 2
// 254.097 us; speedup vs baseline: 1.0559x; 1.0559x over previous
//
#include <hip/hip_runtime.h>
#include <stdint.h>

// Problem constants (from reference)
#define N_B   512
#define D_K   512
#define C_N   50000
#define C_PAD 50048        // padded to 391*128
#define BM    128
#define BN    128
#define BK    32
#define NCB   391          // ceil(C_N / BN)
#define NWG   (NCB * 4)    // 1564 workgroups, 1D grid

#define S_SCALE 30.0f
#define COS_Mc  0.87758256189037276f
#define SIN_Mc  0.47942553860420301f
#define TH_Cc  (-0.87758256189037276f)
#define MM_Cc   0.23971276930210156f
#define NEG_BIG (-3.0e38f)

typedef __attribute__((ext_vector_type(8))) __bf16 bf16x8;
typedef __attribute__((ext_vector_type(4))) float  f32x4;

__device__ __forceinline__ unsigned short f2bf(float f) {
    union { float f; unsigned u; } v; v.f = f;
    unsigned r = v.u + 0x7FFFu + ((v.u >> 16) & 1u);   // RNE
    return (unsigned short)(r >> 16);
}

__device__ __forceinline__ void gl2lds16(const void* g, void* l) {
    __builtin_amdgcn_global_load_lds(
        (__attribute__((address_space(1))) unsigned int*)(g),
        (__attribute__((address_space(3))) unsigned int*)(l),
        16, 0, 0);
}

// One wave per row: exact fp32 inverse L2 norm + bf16 conversion.
// Rows in [nvalid, ntotal) are zero padding (invw=0, wb row = 0).
__global__ __launch_bounds__(256) void prep_kernel(
        const float* __restrict__ src, unsigned short* __restrict__ dstb,
        float* __restrict__ inv, int nvalid, int ntotal)
{
    int wave = threadIdx.x >> 6, lane = threadIdx.x & 63;
    int row = blockIdx.x * 4 + wave;
    if (row >= ntotal) return;
    unsigned short* dst = dstb + (size_t)row * D_K + lane * 8;
    if (row < nvalid) {
        const float4* s4 = (const float4*)(src + (size_t)row * D_K) + lane * 2;
        float4 a = s4[0], b = s4[1];
        float ss = a.x*a.x + a.y*a.y + a.z*a.z + a.w*a.w
                 + b.x*b.x + b.y*b.y + b.z*b.z + b.w*b.w;
        #pragma unroll
        for (int off = 32; off >= 1; off >>= 1) ss += __shfl_xor(ss, off, 64);
        if (lane == 0) inv[row] = 1.0f / fmaxf(sqrtf(ss), 1e-12f);
        uint4 o;
        o.x = (unsigned)f2bf(a.x) | ((unsigned)f2bf(a.y) << 16);
        o.y = (unsigned)f2bf(a.z) | ((unsigned)f2bf(a.w) << 16);
        o.z = (unsigned)f2bf(b.x) | ((unsigned)f2bf(b.y) << 16);
        o.w = (unsigned)f2bf(b.z) | ((unsigned)f2bf(b.w) << 16);
        *(uint4*)dst = o;
    } else {
        *(uint4*)dst = make_uint4(0u, 0u, 0u, 0u);
        if (lane == 0) inv[row] = 0.0f;
    }
}

// 128x128 tile GEMM (B^T layout), bf16 MFMA 16x16x32.
// v3: safe 2-phase pipeline (guide T3 minimum recipe) — double-buffered LDS,
// STAGE(t+1) issued BEFORE COMPUTE(t), single __syncthreads() per K-step
// (its vmcnt(0) drain lands after the compute, not right after load issue).
// No hand-rolled barriers => no LDS-reuse race. Plus: 1D grid with rb-fastest
// decode + bijective XCD swizzle (B panel fetched ~once), nontemporal out
// stores, max-then-sum epilogue reduction.
__global__ __launch_bounds__(256) void gemm_margin_kernel(
        const unsigned short* __restrict__ xb, const unsigned short* __restrict__ wb,
        const float* __restrict__ invx, const float* __restrict__ invw,
        const int* __restrict__ labels, float* __restrict__ out,
        float* __restrict__ m_part, float* __restrict__ s_part)
{
    // Bijective XCD swizzle (m204 form): NWG = 1564 = 8*195 + 4.
    const int orig = blockIdx.x;
    const int qch = NWG >> 3, rch = NWG & 7;
    const int xcd = orig & 7, idx = orig >> 3;
    const int wg = (xcd < rch ? xcd * (qch + 1)
                              : rch * (qch + 1) + (xcd - rch) * qch) + idx;
    const int cb = wg >> 2, rb = wg & 3;   // rb fastest: 4 rbs of a cb adjacent
    const int m0 = rb * BM, c0 = cb * BN;
    const int tid = threadIdx.x;
    const int lane = tid & 63, wave = tid >> 6;
    const int wm = wave >> 1, wn = wave & 1;
    const int l15 = lane & 15, q = lane >> 4;

    __shared__ __align__(16) unsigned short As[2][BM * BK];
    __shared__ __align__(16) unsigned short Bs[2][BN * BK];
    __shared__ float s_invx[BM];
    __shared__ float s_invw[BN];
    __shared__ int   s_lab[BM];
    __shared__ float sm[2][BM];
    __shared__ float ssm[2][BM];

    f32x4 zero4 = {0.f, 0.f, 0.f, 0.f};
    f32x4 acc[4][4];
    #pragma unroll
    for (int i = 0; i < 4; i++)
        #pragma unroll
        for (int j = 0; j < 4; j++) acc[i][j] = zero4;

    // Staging: thread t stages 16B chunks; LDS byte offset = tid*16 within a
    // buffer (wave-uniform base + lane*16, as gl2lds requires). XOR k-chunk
    // swizzle applied on the GLOBAL source so LDS dest stays identity order.
    const int srow   = tid >> 2;       // 0..63
    const int pchunk = tid & 3;        // physical chunk slot in LDS row
    const int lch0 = pchunk ^ ((srow >> 1) & 3);
    const int lch1 = pchunk ^ (((srow + 64) >> 1) & 3);

    const unsigned short* gA0 = xb + (size_t)(m0 + srow)      * D_K + lch0 * 8;
    const unsigned short* gA1 = xb + (size_t)(m0 + srow + 64) * D_K + lch1 * 8;
    const unsigned short* gB0 = wb + (size_t)(c0 + srow)      * D_K + lch0 * 8;
    const unsigned short* gB1 = wb + (size_t)(c0 + srow + 64) * D_K + lch1 * 8;

    const int off0 = srow * BK + pchunk * 8;
    const int off1 = (srow + 64) * BK + pchunk * 8;

    // Fragment read offsets (same swizzle): A[m=l15][k=q*8+j]
    int aoff[4], boff[4];
    #pragma unroll
    for (int i = 0; i < 4; i++) {
        int Ra = wm * 64 + i * 16 + l15;
        aoff[i] = Ra * BK + (q ^ ((Ra >> 1) & 3)) * 8;
        int Rb = wn * 64 + i * 16 + l15;
        boff[i] = Rb * BK + (q ^ ((Rb >> 1) & 3)) * 8;
    }

#define STAGE(b, k0) do {                       \
        gl2lds16(gA0 + (k0), &As[b][off0]);     \
        gl2lds16(gA1 + (k0), &As[b][off1]);     \
        gl2lds16(gB0 + (k0), &Bs[b][off0]);     \
        gl2lds16(gB1 + (k0), &Bs[b][off1]);     \
    } while (0)

#define COMPUTE(b) do {                                                       \
        bf16x8 af_[4], bf_[4];                                                \
        _Pragma("unroll")                                                     \
        for (int i = 0; i < 4; i++) af_[i] = *(const bf16x8*)(&As[b][aoff[i]]); \
        _Pragma("unroll")                                                     \
        for (int i = 0; i < 4; i++) bf_[i] = *(const bf16x8*)(&Bs[b][boff[i]]); \
        _Pragma("unroll")                                                     \
        for (int mi = 0; mi < 4; mi++)                                        \
            _Pragma("unroll")                                                 \
            for (int ni = 0; ni < 4; ni++)                                    \
                acc[mi][ni] = __builtin_amdgcn_mfma_f32_16x16x32_bf16(        \
                                  af_[mi], bf_[ni], acc[mi][ni], 0, 0, 0);    \
    } while (0)

    // Prologue: stage tile 0 + metadata, full drain (__syncthreads emits
    // s_waitcnt vmcnt(0) lgkmcnt(0) before s_barrier).
    STAGE(0, 0);
    if (tid < BM) {
        s_invx[tid] = invx[m0 + tid];
        s_lab[tid]  = labels[m0 + tid];
        s_invw[tid] = invw[c0 + tid];
    }
    __syncthreads();

    // 2-phase K-loop: 16 tiles, 2 LDS buffers, one __syncthreads per tile.
    // Hazards: buf read at t was staged at t-1 (drained by t-1's barrier);
    // buf overwritten by STAGE at t was read at t-1 (ds_reads drained by
    // the same barrier). All compiler-managed — race-free by construction.
    #pragma unroll
    for (int t = 0; t < 16; ++t) {
        const int cur = t & 1;
        if (t < 15) STAGE(cur ^ 1, (t + 1) * BK);   // prefetch next tile
        COMPUTE(cur);                                // hide load under this
        __syncthreads();
    }
#undef STAGE
#undef COMPUTE

    // Epilogue. C/D layout: col = lane&15, row = (lane>>4)*4 + reg  [m89/m91]
    #pragma unroll
    for (int mi = 0; mi < 4; mi++) {
        #pragma unroll
        for (int r = 0; r < 4; r++) {
            int lrow = wm * 64 + mi * 16 + q * 4 + r;
            int grow = m0 + lrow;
            float ivx = s_invx[lrow];
            int lab = s_lab[lrow];
            float tv[4]; bool ok[4];
            float vmax = NEG_BIG;
            #pragma unroll
            for (int ni = 0; ni < 4; ni++) {
                int lcol = wn * 64 + ni * 16 + l15;
                int gcol = c0 + lcol;
                float cosv = acc[mi][ni][r] * ivx * s_invw[lcol];
                float o;
                if (gcol == lab) {
                    float s2 = 1.0f + 1e-7f - cosv * cosv;
                    s2 = fminf(fmaxf(s2, 0.0f), 1.0f);
                    float phi = cosv * COS_Mc - sqrtf(s2) * SIN_Mc;
                    if (!(cosv > TH_Cc)) phi = cosv - MM_Cc;
                    o = S_SCALE * phi;
                } else {
                    o = S_SCALE * cosv;
                }
                ok[ni] = (gcol < C_N);
                tv[ni] = o;
                if (ok[ni]) {
                    __builtin_nontemporal_store(o, &out[(size_t)grow * C_N + gcol]);
                    vmax = fmaxf(vmax, o);
                }
            }
            // Row max across the 16 lanes of the quad (covering 64 cols),
            // then one exp pass + sum reduce (4 exps/lane vs 8 online).
            #pragma unroll
            for (int off = 1; off < 16; off <<= 1)
                vmax = fmaxf(vmax, __shfl_xor(vmax, off, 64));
            float vs = 0.f;
            #pragma unroll
            for (int ni = 0; ni < 4; ni++)
                if (ok[ni]) vs += __expf(tv[ni] - vmax);
            #pragma unroll
            for (int off = 1; off < 16; off <<= 1)
                vs += __shfl_xor(vs, off, 64);
            if (l15 == 0) { sm[wn][lrow] = vmax; ssm[wn][lrow] = vs; }
        }
    }
    __syncthreads();
    if (tid < BM) {
        float m1 = sm[0][tid], s1 = ssm[0][tid];
        float m2 = sm[1][tid], s2 = ssm[1][tid];
        float M = fmaxf(m1, m2);
        float S = s1 * __expf(m1 - M) + s2 * __expf(m2 - M);
        m_part[(size_t)(m0 + tid) * NCB + cb] = M;
        s_part[(size_t)(m0 + tid) * NCB + cb] = S;
    }
}

// Merge the NCB col-block partials per row -> logZ -> per-row loss term.
__global__ void rowreduce_kernel(
        const float* __restrict__ m_part, const float* __restrict__ s_part,
        const float* __restrict__ out, const int* __restrict__ labels,
        float* __restrict__ lossp)
{
    int row = blockIdx.x;
    int lane = threadIdx.x;   // blockDim = 64
    float m = NEG_BIG, s = 0.f;
    for (int j = lane; j < NCB; j += 64) {
        float m2 = m_part[(size_t)row * NCB + j];
        float s2 = s_part[(size_t)row * NCB + j];
        float M = fmaxf(m, m2);
        s = s * __expf(m - M) + s2 * __expf(m2 - M);
        m = M;
    }
    #pragma unroll
    for (int off = 1; off < 64; off <<= 1) {
        float om = __shfl_xor(m, off, 64);
        float os = __shfl_xor(s, off, 64);
        float M = fmaxf(m, om);
        s = s * __expf(m - M) + os * __expf(om - M);
        m = M;
    }
    if (lane == 0) {
        float logZ = m + logf(s);
        int lab = labels[row];
        lossp[row] = logZ - out[(size_t)row * C_N + lab];
    }
}

__global__ void loss_kernel(const float* __restrict__ lossp, float* __restrict__ loss_out) {
    int t = threadIdx.x;   // blockDim = 256
    float v = lossp[t] + lossp[t + 256];
    #pragma unroll
    for (int off = 32; off >= 1; off >>= 1) v += __shfl_xor(v, off, 64);
    __shared__ float part[4];
    if ((t & 63) == 0) part[t >> 6] = v;
    __syncthreads();
    if (t == 0) loss_out[0] = (part[0] + part[1] + part[2] + part[3]) * (1.0f / 512.0f);
}

extern "C" void kernel_launch(void* const* d_in, const int* in_sizes, int n_in,
                              void* d_out, int out_size, void* d_ws, size_t ws_size,
                              hipStream_t stream)
{
    const float* x      = (const float*)d_in[0];
    const int*   labels = (const int*)d_in[1];
    const float* w      = (const float*)d_in[2];
    float* out = (float*)d_out;
    float* loss_out = out + (size_t)N_B * C_N;

    char* ws = (char*)d_ws;
    size_t off = 0;
    unsigned short* xb = (unsigned short*)(ws + off); off += (size_t)N_B * D_K * 2;     // 512 KB
    unsigned short* wb = (unsigned short*)(ws + off); off += (size_t)C_PAD * D_K * 2;   // 51.2 MB
    float* invx   = (float*)(ws + off); off += (size_t)N_B * 4;
    float* invw   = (float*)(ws + off); off += (size_t)C_PAD * 4;
    float* m_part = (float*)(ws + off); off += (size_t)N_B * NCB * 4;
    float* s_part = (float*)(ws + off); off += (size_t)N_B * NCB * 4;
    float* lossp  = (float*)(ws + off); off += (size_t)N_B * 4;

    prep_kernel<<<N_B / 4, 256, 0, stream>>>(x, xb, invx, N_B, N_B);
    prep_kernel<<<C_PAD / 4, 256, 0, stream>>>(w, wb, invw, C_N, C_PAD);
    gemm_margin_kernel<<<dim3(NWG), 256, 0, stream>>>(xb, wb, invx, invw, labels,
                                                      out, m_part, s_part);
    rowreduce_kernel<<<N_B, 64, 0, stream>>>(m_part, s_part, out, labels, lossp);
    loss_kernel<<<1, 256, 0, stream>>>(lossp, loss_out);
}